// Round 1
// baseline (249.437 us; speedup 1.0000x reference)
//
#include <hip/hip_runtime.h>

// Problem constants (reference: B=32, N=1024, D=384, max_len=4096)
#define BB 32
#define NN 1024
#define DD 384
#define ML 4096
#define D4 (DD / 4)            // 96 float4 per row
#define RPB 32                 // output rows per block
#define GT 256                 // threads per block (4 waves)
#define F4PT (RPB * D4 / GT)   // 12 float4 per thread
#define NBLK (BB * ML / RPB)   // 4096 blocks (divisible by 8 -> bijective XCD swizzle)
#define NW (GT / 64)           // 4 waves per block

typedef float f32x4 __attribute__((ext_vector_type(4)));

// Single fused kernel.
// Phase A (per block, ~2 barriers): redundant per-batch cumsum of durations.
//   - 256 threads load 1024 ints as int4 (4 KB; L2-resident after first touch
//     per batch -> HBM cost is only the real 128 KB).
//   - wave-level inclusive scan via __shfl_up (6 steps, no LDS, no barrier),
//     cross-wave combine via 4-entry LDS (1 barrier), element cums to LDS.
// Phase B: 32 lanes binary-search (searchsorted right) their own t rows in LDS.
// Phase C: the proven streaming gather, unchanged memory pattern:
//   per-wave stores are contiguous 1 KB, x reads row-coherent, XCD swizzle
//   keeps each XCD's x slice ~6 MB (L2-friendly). Stores nontemporal: the
//   output is never re-read, keep L2 for x.
__global__ __launch_bounds__(GT) void lr_fused_kernel(
    const float4* __restrict__ x, const int4* __restrict__ dur4,
    float4* __restrict__ out, float* __restrict__ mask) {
    __shared__ __align__(16) int cum[NN];   // 4 KB
    __shared__ int wsum[NW];
    __shared__ int idxs[RPB];

    // XCD-aware swizzle: contiguous run of output rows per XCD (perf only).
    const int g    = ((blockIdx.x & 7) * (NBLK / 8)) + (blockIdx.x >> 3);
    const int row0 = g * RPB;               // global output row
    const int b    = row0 >> 12;            // row / ML
    const int t0   = row0 & (ML - 1);       // t within batch
    const int tid  = threadIdx.x;
    const int lane = tid & 63;
    const int wid  = tid >> 6;

    // ---- Phase A: scan ----
    int4 d = dur4[b * (NN / 4) + tid];      // 256 * int4 = 1024 durations
    int s = d.x + d.y + d.z + d.w;          // this thread's 4-elem sum
    #pragma unroll
    for (int off = 1; off < 64; off <<= 1) {
        int n = __shfl_up(s, off);
        if (lane >= off) s += n;            // wave-inclusive scan of 4-sums
    }
    if (lane == 63) wsum[wid] = s;
    __syncthreads();
    int woff = 0;
    #pragma unroll
    for (int w = 0; w < NW - 1; ++w)
        if (w < wid) woff += wsum[w];
    int4 c;                                  // element-level inclusive cums
    c.w = woff + s;
    c.z = c.w - d.w;
    c.y = c.z - d.z;
    c.x = c.y - d.y;
    reinterpret_cast<int4*>(cum)[tid] = c;   // contiguous 16 B LDS store
    __syncthreads();

    // ---- Phase B: searchsorted(cum, t, 'right') for this block's 32 rows ----
    const int total = cum[NN - 1];
    if (tid < RPB) {
        const int t = t0 + tid;
        int idx = -1;
        if (t < total) {
            int pos = 0;                     // count of cum[i] <= t
            #pragma unroll
            for (int step = 512; step > 0; step >>= 1) {
                const int np = pos + step;
                if (np <= NN && cum[np - 1] <= t) pos = np;
            }
            idx = (pos < NN) ? pos : NN - 1; // clamp (unreachable when t<total)
        }
        idxs[tid] = idx;
        mask[b * ML + t] = (idx < 0) ? 1.0f : 0.0f;
    }
    __syncthreads();

    // ---- Phase C: streaming gather (unchanged pattern) ----
    #pragma unroll
    for (int k = 0; k < F4PT; ++k) {
        const int pos = tid + k * GT;        // 0 .. RPB*D4-1
        const int r   = pos / D4;            // const-div -> magic mul
        const int d4  = pos - r * D4;
        const int idx = idxs[r];             // LDS broadcast (<=2 rows/wave)
        float4 v = {0.0f, 0.0f, 0.0f, 0.0f};
        if (idx >= 0) v = x[((size_t)b * NN + idx) * D4 + d4];
        f32x4* dst = reinterpret_cast<f32x4*>(&out[(size_t)(row0 + r) * D4 + d4]);
        __builtin_nontemporal_store(*reinterpret_cast<const f32x4*>(&v), dst);
    }
}

extern "C" void kernel_launch(void* const* d_in, const int* in_sizes, int n_in,
                              void* d_out, int out_size, void* d_ws, size_t ws_size,
                              hipStream_t stream) {
    const float* x = (const float*)d_in[0];
    const int* dur = (const int*)d_in[1];
    // d_in[2] is max_len scalar; fixed at 4096 for this problem instance.

    float* out  = (float*)d_out;                   // (B, ML, D) fp32
    float* mask = out + (size_t)BB * ML * DD;      // (B, ML) as fp32 0/1

    lr_fused_kernel<<<NBLK, GT, 0, stream>>>(
        (const float4*)x, (const int4*)dur, (float4*)out, mask);
}